// Round 1
// 323.246 us; speedup vs baseline: 1.0178x; 1.0178x over previous
//
#include <hip/hip_runtime.h>
#include <hip/hip_bf16.h>

typedef __attribute__((ext_vector_type(8))) short bf16x8;
typedef __attribute__((ext_vector_type(4))) float f32x4;

#define T_SEQ   512
#define B_BATCH 128
#define H_DIM   64
#define MB      64               // rows (t*B+b) per block
#define AS_STRIDE 136            // bf16 per row of A split-plane (128 + 8 pad; 272B, 16B-mult)
#define ZS_STRIDE 193            // f32 per row of z tile (192 + 1 pad)
#define A2S       72             // bf16 per row of layer-2 A split-plane (64 + 8 pad; 144B)
#define LASTROW ((T_SEQ - 1) * B_BATCH)   // 65408

// ws layout (shorts): W0 gate-rows (192x512) planes h/m/l, then W1 (192x64) h/m/l
#define W0H 0
#define W0M 98304
#define W0L 196608
#define W1H 294912
#define W1M 307200
#define W1L 319488
// total 331776 shorts = 663552 bytes of d_ws

// truncation 3-way split: f = h + m + l + r, |r| <= ~2^-24 |f|; subtractions exact
__device__ __forceinline__ void tsplit(float f, unsigned& h, unsigned& m, unsigned& l) {
    unsigned uf = __builtin_bit_cast(unsigned, f);
    h = uf >> 16;
    float hf = __builtin_bit_cast(float, uf & 0xFFFF0000u);
    float r1 = f - hf;
    unsigned u1 = __builtin_bit_cast(unsigned, r1);
    m = u1 >> 16;
    float mf = __builtin_bit_cast(float, u1 & 0xFFFF0000u);
    float r2 = r1 - mf;
    l = __builtin_bit_cast(unsigned, r2) >> 16;
}

// split two floats, pack into one dword per plane (elem0 low, elem1 high)
__device__ __forceinline__ void tsplit2(float a, float b,
                                        unsigned& ph, unsigned& pm, unsigned& pl) {
    unsigned ha, ma, la, hb, mb, lb;
    tsplit(a, ha, ma, la);
    tsplit(b, hb, mb, lb);
    ph = ha | (hb << 16);
    pm = ma | (mb << 16);
    pl = la | (lb << 16);
}

// 6-product accumulate: (h1+m1+l1)(h2+m2+l2), dropping ml, lm, ll (~2^-24 |ab|)
__device__ __forceinline__ f32x4 mfma6(bf16x8 ah, bf16x8 am, bf16x8 al,
                                       bf16x8 bh, bf16x8 bm, bf16x8 bl, f32x4 c) {
    c = __builtin_amdgcn_mfma_f32_16x16x32_bf16(ah, bh, c, 0, 0, 0);
    c = __builtin_amdgcn_mfma_f32_16x16x32_bf16(ah, bm, c, 0, 0, 0);
    c = __builtin_amdgcn_mfma_f32_16x16x32_bf16(am, bh, c, 0, 0, 0);
    c = __builtin_amdgcn_mfma_f32_16x16x32_bf16(ah, bl, c, 0, 0, 0);
    c = __builtin_amdgcn_mfma_f32_16x16x32_bf16(al, bh, c, 0, 0, 0);
    c = __builtin_amdgcn_mfma_f32_16x16x32_bf16(am, bm, c, 0, 0, 0);
    return c;
}

// branch-free Cody-Waite cos, ~1 ulp for |x| <~ 30 (args here are |z+bt| <~ 9).
// 3-fma pi/2 reduction (CUDA-internal constants) + degree-9/8 sin/cos kernels.
__device__ __forceinline__ float fast_cos(float x) {
    float n = rintf(x * 0.6366197723675814f);          // 2/pi
    int   m = (int)n;
    float r = __builtin_fmaf(n, -1.5707962512969971e+00f, x);
    r = __builtin_fmaf(n, -7.5497894158615964e-08f, r);
    r = __builtin_fmaf(n, -5.3903025299577647e-15f, r);
    float r2 = r * r;
    // sin kernel: r + r^3*(S1 + r2*(S2 + r2*(S3 + r2*S4)))
    float ps = __builtin_fmaf(r2, 2.7557314297e-06f, -1.9841270114e-04f);
    ps = __builtin_fmaf(r2, ps, 8.3333337680e-03f);
    ps = __builtin_fmaf(r2, ps, -1.6666667163e-01f);
    float s = __builtin_fmaf(r * r2, ps, r);
    // cos kernel: 1 + r2*(-0.5 + r2*(C2 + r2*(C3 + r2*C4)))
    float pc = __builtin_fmaf(r2, 2.4801587642e-05f, -1.3888889225e-03f);
    pc = __builtin_fmaf(r2, pc, 4.1666667908e-02f);
    pc = __builtin_fmaf(r2, pc, -0.5f);
    float c = __builtin_fmaf(r2, pc, 1.0f);
    // quadrant: m%4 == 0:c  1:-s  2:-c  3:s
    float v = (m & 1) ? s : c;
    unsigned sign = (unsigned)((m + 1) & 2) << 30;     // 0 or 0x80000000
    return __builtin_bit_cast(float, __builtin_bit_cast(unsigned, v) ^ sign);
}

// sigmoid via native v_exp (~2 ulp) + hw rcp with one Newton step
__device__ __forceinline__ float fast_sigmoid(float x) {
    float e = __expf(-x);
    float d = 1.0f + e;
    float r = __builtin_amdgcn_rcpf(d);
    return r * (2.0f - d * r);
}

// tanh for x >= 0 (args here are in (0,1)): (e^2x - 1)/(e^2x + 1); abs err ~2e-7
__device__ __forceinline__ float fast_tanh_pos(float x) {
    float t = __expf(2.0f * x);
    float d = t + 1.0f;
    float r = __builtin_amdgcn_rcpf(d);
    r = r * (2.0f - d * r);
    return (t - 1.0f) * r;
}

// ---------- kernel 1: pre-split weights into d_ws (runs every launch; ~5 us) ----------
__global__ __launch_bounds__(256) void presplit_w(const float* __restrict__ W0,
                                                  const float* __restrict__ W1,
                                                  short* __restrict__ ws) {
    int i = blockIdx.x * 256 + threadIdx.x;
    if (i < 98304) {                      // W0 gates 1..3: flat rows 64..255, stride 576
        int r = i >> 9, k = i & 511;
        unsigned h, m, l;
        tsplit(W0[(r + 64) * 576 + k], h, m, l);
        ws[W0H + i] = (short)h;
        ws[W0M + i] = (short)m;
        ws[W0L + i] = (short)l;
    } else if (i < 110592) {              // W1 gates 1..3: rows 64..255, stride 128, k<64
        int j = i - 98304;
        int r = j >> 6, k = j & 63;
        unsigned h, m, l;
        tsplit(W1[(r + 64) * 128 + k], h, m, l);
        ws[W1H + j] = (short)h;
        ws[W1M + j] = (short)m;
        ws[W1L + j] = (short)l;
    }
}

// ---------- kernel 2: fused QLSTM ----------
// LDS layout (total 53760 B -> 3 blocks/CU):
//   [0, 52224)      union: A1 split-planes ah/am/al [64][136] bf16 (3 x 17408 B)
//                          | zs [64][193] f32 (49408 B)
//                          | A2 split-planes [64][72] bf16 x3 (27648 B)
//   [52224, 52992)  bt0 [192] f32   (b0+th0, gates 1..3)
//   [52992, 53760)  bt1 [192] f32
__global__ __launch_bounds__(256, 3) void qlstm_fused(
    const float* __restrict__ x,
    const float* __restrict__ b0,
    const float* __restrict__ th0,
    const float* __restrict__ g0,
    const float* __restrict__ be0,
    const float* __restrict__ b1,
    const float* __restrict__ th1,
    const float* __restrict__ g1,
    const float* __restrict__ be1,
    const short* __restrict__ wsp,      // pre-split weight planes
    float* __restrict__ out)
{
    __shared__ __align__(16) char lds[53760];
    short* ah = (short*)lds;                      // [64][136]
    short* am = ah + 64 * AS_STRIDE;
    short* al = am + 64 * AS_STRIDE;
    float* zs  = (float*)lds;                     // [64][193] (aliases planes)
    short* a2h = (short*)lds;                     // [64][72]  (aliases zs; layer-2 A)
    short* a2m = a2h + 64 * A2S;
    short* a2l = a2m + 64 * A2S;
    float* bt0 = (float*)(lds + 52224);           // [192]
    float* bt1 = bt0 + 192;                       // [192]

    const int tid = threadIdx.x;
    const long rowbase = (long)blockIdx.x * MB;

    float* out0 = out;                                      // h1      [T*B][64]
    float* out1 = out + (long)T_SEQ * B_BATCH * H_DIM;      // h0[-1]  [128][64]
    float* out2 = out1 + B_BATCH * H_DIM;                   // c0[-1]
    float* out3 = out2 + B_BATCH * H_DIM;                   // h1[-1]
    float* out4 = out3 + B_BATCH * H_DIM;                   // c1[-1]

    // stage combined bias + theta for gates 1..3 (flat row in (4,64) = 64 + gc)
    if (tid < 192) {
        bt0[tid] = b0[64 + tid] + th0[64 + tid];
        bt1[tid] = b1[64 + tid] + th1[64 + tid];
    }

    const int lane = tid & 63;
    const int wave = tid >> 6;
    const int ln   = lane & 15;   // MFMA m/n lane index
    const int quad = lane >> 4;   // MFMA k-group / row-group
    const int cw   = wave * 48;   // this wave's N-column base (192 cols / 4 waves)

    // B plane row offsets (in shorts) for this wave's 3 column-tiles
    int brow0[3], brow1[3];
    for (int nt = 0; nt < 3; ++nt) {
        int gc = cw + nt * 16 + ln;
        brow0[nt] = gc * 512;
        brow1[nt] = gc * 64;
    }

    // ------- GEMM1: z0[64][192] = x[64][512] . W0g^T, pre-split planes, K chunks of 128
    f32x4 acc[4][3];
    for (int mt = 0; mt < 4; ++mt)
        for (int nt = 0; nt < 3; ++nt)
            acc[mt][nt] = (f32x4){0.f, 0.f, 0.f, 0.f};

    for (int kc = 0; kc < 512; kc += 128) {
        // stage + split x chunk [64][128] -> 3 bf16 planes (each element split ONCE)
        for (int pass = 0; pass < 4; ++pass) {
            int e  = pass * 256 + tid;      // 0..1023 covers 1024*8 = 8192 elements
            int r  = e >> 4;                // row 0..63
            int k8 = (e & 15) << 3;         // col 0,8,...,120
            const float* xp = x + (rowbase + r) * 512 + kc + k8;
            float4 f0 = *(const float4*)xp;
            float4 f1 = *(const float4*)(xp + 4);
            uint4 Ph, Pm, Pl;
            tsplit2(f0.x, f0.y, Ph.x, Pm.x, Pl.x);
            tsplit2(f0.z, f0.w, Ph.y, Pm.y, Pl.y);
            tsplit2(f1.x, f1.y, Ph.z, Pm.z, Pl.z);
            tsplit2(f1.z, f1.w, Ph.w, Pm.w, Pl.w);
            int ao = r * AS_STRIDE + k8;
            *(uint4*)(ah + ao) = Ph;
            *(uint4*)(am + ao) = Pm;
            *(uint4*)(al + ao) = Pl;
        }
        __syncthreads();
        for (int k0 = 0; k0 < 128; k0 += 32) {
            int ka = k0 + quad * 8;
            bf16x8 Ah[4], Am[4], Al[4];
            for (int mt = 0; mt < 4; ++mt) {
                int ao = (mt * 16 + ln) * AS_STRIDE + ka;
                Ah[mt] = *(const bf16x8*)(ah + ao);
                Am[mt] = *(const bf16x8*)(am + ao);
                Al[mt] = *(const bf16x8*)(al + ao);
            }
            for (int nt = 0; nt < 3; ++nt) {
                int bo = brow0[nt] + kc + ka;
                bf16x8 Bh = *(const bf16x8*)(wsp + W0H + bo);
                bf16x8 Bm = *(const bf16x8*)(wsp + W0M + bo);
                bf16x8 Bl = *(const bf16x8*)(wsp + W0L + bo);
                for (int mt = 0; mt < 4; ++mt)
                    acc[mt][nt] = mfma6(Ah[mt], Am[mt], Al[mt], Bh, Bm, Bl, acc[mt][nt]);
            }
        }
        __syncthreads();   // plane reads done before next stage / zs overwrite
    }

    // epilogue: D[m][n]: col = lane&15, row = quad*4 + reg  [measured m89/m91]
    for (int mt = 0; mt < 4; ++mt)
        for (int nt = 0; nt < 3; ++nt)
            for (int i = 0; i < 4; ++i) {
                int row = mt * 16 + quad * 4 + i;
                int col = cw + nt * 16 + ln;
                zs[row * ZS_STRIDE + col] = acc[mt][nt][i];
            }
    __syncthreads();

    // ------- cumprod(cos(z + b + th)) layer 0 (wave-uniform: wave 3 idles)
    if (tid < 192) {
        int gi = tid >> 6;
        int r  = tid & 63;
        float* zrow = zs + r * ZS_STRIDE + gi * 64;
        const float* btg = bt0 + gi * 64;
        float p = 1.0f;
        for (int n = 0; n < 64; ++n) {
            p *= fast_cos(zrow[n] + btg[n]);
            zrow[n] = p;
        }
    }
    __syncthreads();

    // ------- gates + two-pass LayerNorm layer 0 -> registers -> split A2 planes
    {
        int r = tid >> 2;            // row 0..63
        int j = tid & 3;             // 16-element chunk
        long tbrow = rowbase + r;
        bool lastt = (tbrow >= LASTROW);
        int bidx = (int)(tbrow - LASTROW);
        const float* zr = zs + r * ZS_STRIDE;
        float h[16];
        float s = 0.f;
        for (int i = 0; i < 16; ++i) {
            int n = j * 16 + i;
            float q1 = zr[n];            // gate 1 (input)
            float q2 = zr[64 + n];       // gate 2 (update)
            float q3 = zr[128 + n];      // gate 3 (output)
            float ig = fast_sigmoid(q1);
            float gg = fast_tanh_pos(fast_sigmoid(q2));
            float og = fast_sigmoid(q3);
            float c  = ig * gg;
            float hv = og * fast_tanh_pos(c);
            h[i] = hv;
            s += hv;
            if (lastt) out2[bidx * 64 + n] = c;
        }
        s += __shfl_xor(s, 1);  s += __shfl_xor(s, 2);
        float mu = s * (1.0f / 64.0f);
        float s2 = 0.f;
        for (int i = 0; i < 16; ++i) {           // two-pass: matches mean((h-mu)^2)
            float d = h[i] - mu;
            s2 += d * d;
        }
        s2 += __shfl_xor(s2, 1); s2 += __shfl_xor(s2, 2);
        float var = s2 * (1.0f / 64.0f);
        float rs  = rsqrtf(var + 1e-5f);
        float hl[16];
        for (int i = 0; i < 16; ++i) {
            int n = j * 16 + i;
            hl[i] = (h[i] - mu) * rs * g0[n] + be0[n];
            if (lastt) out1[bidx * 64 + n] = hl[i];
        }
        __syncthreads();   // all zs reads done before A2 planes overwrite the region

        // split ONCE into layer-2 A planes (previously re-split 4x inline per wave)
        int ab = r * A2S + j * 16;
        uint4 Ph, Pm, Pl;
        tsplit2(hl[0], hl[1], Ph.x, Pm.x, Pl.x);
        tsplit2(hl[2], hl[3], Ph.y, Pm.y, Pl.y);
        tsplit2(hl[4], hl[5], Ph.z, Pm.z, Pl.z);
        tsplit2(hl[6], hl[7], Ph.w, Pm.w, Pl.w);
        *(uint4*)(a2h + ab) = Ph;
        *(uint4*)(a2m + ab) = Pm;
        *(uint4*)(a2l + ab) = Pl;
        tsplit2(hl[8],  hl[9],  Ph.x, Pm.x, Pl.x);
        tsplit2(hl[10], hl[11], Ph.y, Pm.y, Pl.y);
        tsplit2(hl[12], hl[13], Ph.z, Pm.z, Pl.z);
        tsplit2(hl[14], hl[15], Ph.w, Pm.w, Pl.w);
        *(uint4*)(a2h + ab + 8) = Ph;
        *(uint4*)(a2m + ab + 8) = Pm;
        *(uint4*)(a2l + ab + 8) = Pl;
    }
    __syncthreads();

    // ------- GEMM2: z1[64][192] = h0[64][64] . W1g^T, pre-split A2 planes, K=64
    f32x4 acc2[4][3];
    for (int mt = 0; mt < 4; ++mt)
        for (int nt = 0; nt < 3; ++nt)
            acc2[mt][nt] = (f32x4){0.f, 0.f, 0.f, 0.f};
    for (int k0 = 0; k0 < 64; k0 += 32) {
        int ka = k0 + quad * 8;
        bf16x8 Ah[4], Am[4], Al[4];
        for (int mt = 0; mt < 4; ++mt) {
            int ao = (mt * 16 + ln) * A2S + ka;
            Ah[mt] = *(const bf16x8*)(a2h + ao);
            Am[mt] = *(const bf16x8*)(a2m + ao);
            Al[mt] = *(const bf16x8*)(a2l + ao);
        }
        for (int nt = 0; nt < 3; ++nt) {
            int bo = brow1[nt] + ka;
            bf16x8 Bh = *(const bf16x8*)(wsp + W1H + bo);
            bf16x8 Bm = *(const bf16x8*)(wsp + W1M + bo);
            bf16x8 Bl = *(const bf16x8*)(wsp + W1L + bo);
            for (int mt = 0; mt < 4; ++mt)
                acc2[mt][nt] = mfma6(Ah[mt], Am[mt], Al[mt], Bh, Bm, Bl, acc2[mt][nt]);
        }
    }
    __syncthreads();   // A2 plane reads done before zs epilogue overwrites region
    for (int mt = 0; mt < 4; ++mt)
        for (int nt = 0; nt < 3; ++nt)
            for (int i = 0; i < 4; ++i) {
                int row = mt * 16 + quad * 4 + i;
                int col = cw + nt * 16 + ln;
                zs[row * ZS_STRIDE + col] = acc2[mt][nt][i];
            }
    __syncthreads();

    // ------- cumprod layer 1
    if (tid < 192) {
        int gi = tid >> 6;
        int r  = tid & 63;
        float* zrow = zs + r * ZS_STRIDE + gi * 64;
        const float* btg = bt1 + gi * 64;
        float p = 1.0f;
        for (int n = 0; n < 64; ++n) {
            p *= fast_cos(zrow[n] + btg[n]);
            zrow[n] = p;
        }
    }
    __syncthreads();

    // ------- gates + two-pass LayerNorm layer 1 -> out0 directly (+ out3/out4)
    {
        int r = tid >> 2;
        int j = tid & 3;
        long tbrow = rowbase + r;
        bool lastt = (tbrow >= LASTROW);
        int bidx = (int)(tbrow - LASTROW);
        const float* zr = zs + r * ZS_STRIDE;
        float h[16];
        float s = 0.f;
        for (int i = 0; i < 16; ++i) {
            int n = j * 16 + i;
            float q1 = zr[n];
            float q2 = zr[64 + n];
            float q3 = zr[128 + n];
            float ig = fast_sigmoid(q1);
            float gg = fast_tanh_pos(fast_sigmoid(q2));
            float og = fast_sigmoid(q3);
            float c  = ig * gg;
            float hv = og * fast_tanh_pos(c);
            h[i] = hv;
            s += hv;
            if (lastt) out4[bidx * 64 + n] = c;
        }
        s += __shfl_xor(s, 1);  s += __shfl_xor(s, 2);
        float mu = s * (1.0f / 64.0f);
        float s2 = 0.f;
        for (int i = 0; i < 16; ++i) {
            float d = h[i] - mu;
            s2 += d * d;
        }
        s2 += __shfl_xor(s2, 1); s2 += __shfl_xor(s2, 2);
        float var = s2 * (1.0f / 64.0f);
        float rs  = rsqrtf(var + 1e-5f);
        float o4[16];
        for (int i = 0; i < 16; ++i)
            o4[i] = (h[i] - mu) * rs * g1[j * 16 + i] + be1[j * 16 + i];
        float* dst = out0 + tbrow * 64 + j * 16;
        for (int i4 = 0; i4 < 4; ++i4)
            *(float4*)(dst + i4 * 4) = *(float4*)(o4 + i4 * 4);
        if (lastt) {
            float* dst3 = out3 + (long)bidx * 64 + j * 16;
            for (int i4 = 0; i4 < 4; ++i4)
                *(float4*)(dst3 + i4 * 4) = *(float4*)(o4 + i4 * 4);
        }
    }
}

extern "C" void kernel_launch(void* const* d_in, const int* in_sizes, int n_in,
                              void* d_out, int out_size, void* d_ws, size_t ws_size,
                              hipStream_t stream) {
    const float* x   = (const float*)d_in[0];
    const float* W0  = (const float*)d_in[1];
    const float* b0  = (const float*)d_in[2];
    const float* th0 = (const float*)d_in[3];
    const float* g0  = (const float*)d_in[4];
    const float* be0 = (const float*)d_in[5];
    const float* W1  = (const float*)d_in[6];
    const float* b1  = (const float*)d_in[7];
    const float* th1 = (const float*)d_in[8];
    const float* g1  = (const float*)d_in[9];
    const float* be1 = (const float*)d_in[10];
    short* wsp = (short*)d_ws;     // needs 663552 B

    presplit_w<<<dim3(432), dim3(256), 0, stream>>>(W0, W1, wsp);
    qlstm_fused<<<dim3(1024), dim3(256), 0, stream>>>(
        x, b0, th0, g0, be0, b1, th1, g1, be1, wsp, (float*)d_out);
}

// Round 2
// 321.903 us; speedup vs baseline: 1.0220x; 1.0042x over previous
//
#include <hip/hip_runtime.h>
#include <hip/hip_bf16.h>

typedef __attribute__((ext_vector_type(8))) short bf16x8;
typedef __attribute__((ext_vector_type(4))) float f32x4;

#define T_SEQ   512
#define B_BATCH 128
#define H_DIM   64
#define MB      64               // rows (t*B+b) per block
#define A1S     72               // bf16 per row of A split-plane (64 + 8 pad; 144B = 9x16B)
#define ZS_STRIDE 193            // f32 per row of z tile (192 + 1 pad)
#define A2S       72             // bf16 per row of layer-2 A split-plane (64 + 8 pad; 144B)
#define LASTROW ((T_SEQ - 1) * B_BATCH)   // 65408

// ws layout (shorts): W0 gate-rows (192x512) planes h/m/l, then W1 (192x64) h/m/l
#define W0H 0
#define W0M 98304
#define W0L 196608
#define W1H 294912
#define W1M 307200
#define W1L 319488
// total 331776 shorts = 663552 bytes of d_ws

// truncation 3-way split: f = h + m + l + r, |r| <= ~2^-24 |f|; subtractions exact
__device__ __forceinline__ void tsplit(float f, unsigned& h, unsigned& m, unsigned& l) {
    unsigned uf = __builtin_bit_cast(unsigned, f);
    h = uf >> 16;
    float hf = __builtin_bit_cast(float, uf & 0xFFFF0000u);
    float r1 = f - hf;
    unsigned u1 = __builtin_bit_cast(unsigned, r1);
    m = u1 >> 16;
    float mf = __builtin_bit_cast(float, u1 & 0xFFFF0000u);
    float r2 = r1 - mf;
    l = __builtin_bit_cast(unsigned, r2) >> 16;
}

// split two floats, pack into one dword per plane (elem0 low, elem1 high)
__device__ __forceinline__ void tsplit2(float a, float b,
                                        unsigned& ph, unsigned& pm, unsigned& pl) {
    unsigned ha, ma, la, hb, mb, lb;
    tsplit(a, ha, ma, la);
    tsplit(b, hb, mb, lb);
    ph = ha | (hb << 16);
    pm = ma | (mb << 16);
    pl = la | (lb << 16);
}

// split 16 floats (4 float4) into 3 planes at shorts-offset ao (row-contiguous 16 cols)
__device__ __forceinline__ void split16(const float4 f[4],
                                        short* __restrict__ ah, short* __restrict__ am,
                                        short* __restrict__ al, int ao) {
    uint4 Ph, Pm, Pl;
    tsplit2(f[0].x, f[0].y, Ph.x, Pm.x, Pl.x);
    tsplit2(f[0].z, f[0].w, Ph.y, Pm.y, Pl.y);
    tsplit2(f[1].x, f[1].y, Ph.z, Pm.z, Pl.z);
    tsplit2(f[1].z, f[1].w, Ph.w, Pm.w, Pl.w);
    *(uint4*)(ah + ao) = Ph;
    *(uint4*)(am + ao) = Pm;
    *(uint4*)(al + ao) = Pl;
    tsplit2(f[2].x, f[2].y, Ph.x, Pm.x, Pl.x);
    tsplit2(f[2].z, f[2].w, Ph.y, Pm.y, Pl.y);
    tsplit2(f[3].x, f[3].y, Ph.z, Pm.z, Pl.z);
    tsplit2(f[3].z, f[3].w, Ph.w, Pm.w, Pl.w);
    *(uint4*)(ah + ao + 8) = Ph;
    *(uint4*)(am + ao + 8) = Pm;
    *(uint4*)(al + ao + 8) = Pl;
}

// 6-product accumulate: (h1+m1+l1)(h2+m2+l2), dropping ml, lm, ll (~2^-24 |ab|)
__device__ __forceinline__ f32x4 mfma6(bf16x8 ah, bf16x8 am, bf16x8 al,
                                       bf16x8 bh, bf16x8 bm, bf16x8 bl, f32x4 c) {
    c = __builtin_amdgcn_mfma_f32_16x16x32_bf16(ah, bh, c, 0, 0, 0);
    c = __builtin_amdgcn_mfma_f32_16x16x32_bf16(ah, bm, c, 0, 0, 0);
    c = __builtin_amdgcn_mfma_f32_16x16x32_bf16(am, bh, c, 0, 0, 0);
    c = __builtin_amdgcn_mfma_f32_16x16x32_bf16(ah, bl, c, 0, 0, 0);
    c = __builtin_amdgcn_mfma_f32_16x16x32_bf16(al, bh, c, 0, 0, 0);
    c = __builtin_amdgcn_mfma_f32_16x16x32_bf16(am, bm, c, 0, 0, 0);
    return c;
}

// branch-free Cody-Waite cos, ~1 ulp for |x| <~ 30 (args here are |z+bt| <~ 9).
__device__ __forceinline__ float fast_cos(float x) {
    float n = rintf(x * 0.6366197723675814f);          // 2/pi
    int   m = (int)n;
    float r = __builtin_fmaf(n, -1.5707962512969971e+00f, x);
    r = __builtin_fmaf(n, -7.5497894158615964e-08f, r);
    r = __builtin_fmaf(n, -5.3903025299577647e-15f, r);
    float r2 = r * r;
    float ps = __builtin_fmaf(r2, 2.7557314297e-06f, -1.9841270114e-04f);
    ps = __builtin_fmaf(r2, ps, 8.3333337680e-03f);
    ps = __builtin_fmaf(r2, ps, -1.6666667163e-01f);
    float s = __builtin_fmaf(r * r2, ps, r);
    float pc = __builtin_fmaf(r2, 2.4801587642e-05f, -1.3888889225e-03f);
    pc = __builtin_fmaf(r2, pc, 4.1666667908e-02f);
    pc = __builtin_fmaf(r2, pc, -0.5f);
    float c = __builtin_fmaf(r2, pc, 1.0f);
    float v = (m & 1) ? s : c;
    unsigned sign = (unsigned)((m + 1) & 2) << 30;     // 0 or 0x80000000
    return __builtin_bit_cast(float, __builtin_bit_cast(unsigned, v) ^ sign);
}

// sigmoid via native v_exp (~2 ulp) + hw rcp with one Newton step
__device__ __forceinline__ float fast_sigmoid(float x) {
    float e = __expf(-x);
    float d = 1.0f + e;
    float r = __builtin_amdgcn_rcpf(d);
    return r * (2.0f - d * r);
}

// tanh for x >= 0 (args here are in (0,1)): (e^2x - 1)/(e^2x + 1); abs err ~2e-7
__device__ __forceinline__ float fast_tanh_pos(float x) {
    float t = __expf(2.0f * x);
    float d = t + 1.0f;
    float r = __builtin_amdgcn_rcpf(d);
    r = r * (2.0f - d * r);
    return (t - 1.0f) * r;
}

// ---------- kernel 1: pre-split weights into d_ws (runs every launch; ~5 us) ----------
__global__ __launch_bounds__(256) void presplit_w(const float* __restrict__ W0,
                                                  const float* __restrict__ W1,
                                                  short* __restrict__ ws) {
    int i = blockIdx.x * 256 + threadIdx.x;
    if (i < 98304) {                      // W0 gates 1..3: flat rows 64..255, stride 576
        int r = i >> 9, k = i & 511;
        unsigned h, m, l;
        tsplit(W0[(r + 64) * 576 + k], h, m, l);
        ws[W0H + i] = (short)h;
        ws[W0M + i] = (short)m;
        ws[W0L + i] = (short)l;
    } else if (i < 110592) {              // W1 gates 1..3: rows 64..255, stride 128, k<64
        int j = i - 98304;
        int r = j >> 6, k = j & 63;
        unsigned h, m, l;
        tsplit(W1[(r + 64) * 128 + k], h, m, l);
        ws[W1H + j] = (short)h;
        ws[W1M + j] = (short)m;
        ws[W1L + j] = (short)l;
    }
}

// ---------- kernel 2: fused QLSTM ----------
// LDS layout (total 50944 B -> 3 blocks/CU with ~10KB slack):
//   [0, 49408)      union: A1 split-planes ah/am/al [64][72] bf16 (3 x 9216 = 27648)
//                          | zs [64][193] f32 (49408)
//                          | A2 split-planes [64][72] bf16 x3 (27648)
//   [49408, 50176)  bt0 [192] f32   (b0+th0, gates 1..3)
//   [50176, 50944)  bt1 [192] f32
__global__ __launch_bounds__(256, 3) void qlstm_fused(
    const float* __restrict__ x,
    const float* __restrict__ b0,
    const float* __restrict__ th0,
    const float* __restrict__ g0,
    const float* __restrict__ be0,
    const float* __restrict__ b1,
    const float* __restrict__ th1,
    const float* __restrict__ g1,
    const float* __restrict__ be1,
    const short* __restrict__ wsp,      // pre-split weight planes
    float* __restrict__ out)
{
    __shared__ __align__(16) char lds[50944];
    short* ah = (short*)lds;                      // [64][72]
    short* am = ah + 64 * A1S;
    short* al = am + 64 * A1S;
    float* zs  = (float*)lds;                     // [64][193] (aliases planes)
    short* a2h = (short*)lds;                     // [64][72]  (aliases zs; layer-2 A)
    short* a2m = a2h + 64 * A2S;
    short* a2l = a2m + 64 * A2S;
    float* bt0 = (float*)(lds + 49408);           // [192]
    float* bt1 = bt0 + 192;                       // [192]

    const int tid = threadIdx.x;
    const long rowbase = (long)blockIdx.x * MB;

    float* out0 = out;                                      // h1      [T*B][64]
    float* out1 = out + (long)T_SEQ * B_BATCH * H_DIM;      // h0[-1]  [128][64]
    float* out2 = out1 + B_BATCH * H_DIM;                   // c0[-1]
    float* out3 = out2 + B_BATCH * H_DIM;                   // h1[-1]
    float* out4 = out3 + B_BATCH * H_DIM;                   // c1[-1]

    // stage combined bias + theta for gates 1..3 (flat row in (4,64) = 64 + gc)
    if (tid < 192) {
        bt0[tid] = b0[64 + tid] + th0[64 + tid];
        bt1[tid] = b1[64 + tid] + th1[64 + tid];
    }

    const int lane = tid & 63;
    const int wave = tid >> 6;
    const int ln   = lane & 15;   // MFMA m/n lane index
    const int quad = lane >> 4;   // MFMA k-group / row-group
    const int cw   = wave * 48;   // this wave's N-column base (192 cols / 4 waves)

    // B plane row offsets (in shorts) for this wave's 3 column-tiles
    int brow0[3], brow1[3];
    for (int nt = 0; nt < 3; ++nt) {
        int gc = cw + nt * 16 + ln;
        brow0[nt] = gc * 512;
        brow1[nt] = gc * 64;
    }

    // staging geometry: each thread owns 16 contiguous cols of one row per K=64 chunk
    const int sr = tid >> 2;            // row 0..63
    const int sc = (tid & 3) << 4;      // col base 0,16,32,48
    const float* xrow = x + (rowbase + sr) * 512 + sc;
    const int sao = sr * A1S + sc;

    // ------- GEMM1: z0[64][192] = x[64][512] . W0g^T, K chunks of 64, async-staged
    f32x4 acc[4][3];
    #pragma unroll
    for (int mt = 0; mt < 4; ++mt)
        #pragma unroll
        for (int nt = 0; nt < 3; ++nt)
            acc[mt][nt] = (f32x4){0.f, 0.f, 0.f, 0.f};

    {   // prologue: stage chunk 0
        float4 f[4];
        #pragma unroll
        for (int u = 0; u < 4; ++u) f[u] = *(const float4*)(xrow + u * 4);
        split16(f, ah, am, al, sao);
    }
    __syncthreads();

    for (int kc = 0; kc < 512; kc += 64) {
        // T14 async-stage: issue next chunk's global loads BEFORE compute;
        // latency hides under the MFMA phase; split+write after the barrier.
        float4 nf[4];
        const bool more = (kc + 64) < 512;
        if (more) {
            #pragma unroll
            for (int u = 0; u < 4; ++u)
                nf[u] = *(const float4*)(xrow + kc + 64 + u * 4);
        }
        #pragma unroll
        for (int k0 = 0; k0 < 64; k0 += 32) {
            int ka = k0 + quad * 8;
            bf16x8 Ah[4], Am[4], Al[4];
            #pragma unroll
            for (int mt = 0; mt < 4; ++mt) {
                int ao = (mt * 16 + ln) * A1S + ka;
                Ah[mt] = *(const bf16x8*)(ah + ao);
                Am[mt] = *(const bf16x8*)(am + ao);
                Al[mt] = *(const bf16x8*)(al + ao);
            }
            #pragma unroll
            for (int nt = 0; nt < 3; ++nt) {
                int bo = brow0[nt] + kc + ka;
                bf16x8 Bh = *(const bf16x8*)(wsp + W0H + bo);
                bf16x8 Bm = *(const bf16x8*)(wsp + W0M + bo);
                bf16x8 Bl = *(const bf16x8*)(wsp + W0L + bo);
                #pragma unroll
                for (int mt = 0; mt < 4; ++mt)
                    acc[mt][nt] = mfma6(Ah[mt], Am[mt], Al[mt], Bh, Bm, Bl, acc[mt][nt]);
            }
        }
        __syncthreads();   // plane reads done before overwrite / zs epilogue
        if (more) {
            split16(nf, ah, am, al, sao);
            __syncthreads();
        }
    }

    // epilogue: D[m][n]: col = lane&15, row = quad*4 + reg  [measured m89/m91]
    #pragma unroll
    for (int mt = 0; mt < 4; ++mt)
        #pragma unroll
        for (int nt = 0; nt < 3; ++nt)
            #pragma unroll
            for (int i = 0; i < 4; ++i) {
                int row = mt * 16 + quad * 4 + i;
                int col = cw + nt * 16 + ln;
                zs[row * ZS_STRIDE + col] = acc[mt][nt][i];
            }
    __syncthreads();

    // ------- cumprod(cos(z + b + th)) layer 0 (wave-uniform: wave 3 idles)
    if (tid < 192) {
        int gi = tid >> 6;
        int r  = tid & 63;
        float* zrow = zs + r * ZS_STRIDE + gi * 64;
        const float* btg = bt0 + gi * 64;
        float p = 1.0f;
        for (int n = 0; n < 64; ++n) {
            p *= fast_cos(zrow[n] + btg[n]);
            zrow[n] = p;
        }
    }
    __syncthreads();

    // ------- gates + two-pass LayerNorm layer 0 -> registers -> split A2 planes
    {
        int r = tid >> 2;            // row 0..63
        int j = tid & 3;             // 16-element chunk
        long tbrow = rowbase + r;
        bool lastt = (tbrow >= LASTROW);
        int bidx = (int)(tbrow - LASTROW);
        const float* zr = zs + r * ZS_STRIDE;
        float h[16];
        float s = 0.f;
        #pragma unroll
        for (int i = 0; i < 16; ++i) {
            int n = j * 16 + i;
            float q1 = zr[n];            // gate 1 (input)
            float q2 = zr[64 + n];       // gate 2 (update)
            float q3 = zr[128 + n];      // gate 3 (output)
            float ig = fast_sigmoid(q1);
            float gg = fast_tanh_pos(fast_sigmoid(q2));
            float og = fast_sigmoid(q3);
            float c  = ig * gg;
            float hv = og * fast_tanh_pos(c);
            h[i] = hv;
            s += hv;
            if (lastt) out2[bidx * 64 + n] = c;
        }
        s += __shfl_xor(s, 1);  s += __shfl_xor(s, 2);
        float mu = s * (1.0f / 64.0f);
        float s2 = 0.f;
        #pragma unroll
        for (int i = 0; i < 16; ++i) {           // two-pass: matches mean((h-mu)^2)
            float d = h[i] - mu;
            s2 += d * d;
        }
        s2 += __shfl_xor(s2, 1); s2 += __shfl_xor(s2, 2);
        float var = s2 * (1.0f / 64.0f);
        float rs  = rsqrtf(var + 1e-5f);
        float hl[16];
        #pragma unroll
        for (int i = 0; i < 16; ++i) {
            int n = j * 16 + i;
            hl[i] = (h[i] - mu) * rs * g0[n] + be0[n];
            if (lastt) out1[bidx * 64 + n] = hl[i];
        }
        __syncthreads();   // all zs reads done before A2 planes overwrite the region

        // split ONCE into layer-2 A planes
        int ab = r * A2S + j * 16;
        uint4 Ph, Pm, Pl;
        tsplit2(hl[0], hl[1], Ph.x, Pm.x, Pl.x);
        tsplit2(hl[2], hl[3], Ph.y, Pm.y, Pl.y);
        tsplit2(hl[4], hl[5], Ph.z, Pm.z, Pl.z);
        tsplit2(hl[6], hl[7], Ph.w, Pm.w, Pl.w);
        *(uint4*)(a2h + ab) = Ph;
        *(uint4*)(a2m + ab) = Pm;
        *(uint4*)(a2l + ab) = Pl;
        tsplit2(hl[8],  hl[9],  Ph.x, Pm.x, Pl.x);
        tsplit2(hl[10], hl[11], Ph.y, Pm.y, Pl.y);
        tsplit2(hl[12], hl[13], Ph.z, Pm.z, Pl.z);
        tsplit2(hl[14], hl[15], Ph.w, Pm.w, Pl.w);
        *(uint4*)(a2h + ab + 8) = Ph;
        *(uint4*)(a2m + ab + 8) = Pm;
        *(uint4*)(a2l + ab + 8) = Pl;
    }
    __syncthreads();

    // ------- GEMM2: z1[64][192] = h0[64][64] . W1g^T, pre-split A2 planes, K=64
    f32x4 acc2[4][3];
    #pragma unroll
    for (int mt = 0; mt < 4; ++mt)
        #pragma unroll
        for (int nt = 0; nt < 3; ++nt)
            acc2[mt][nt] = (f32x4){0.f, 0.f, 0.f, 0.f};
    #pragma unroll
    for (int k0 = 0; k0 < 64; k0 += 32) {
        int ka = k0 + quad * 8;
        bf16x8 Ah[4], Am[4], Al[4];
        #pragma unroll
        for (int mt = 0; mt < 4; ++mt) {
            int ao = (mt * 16 + ln) * A2S + ka;
            Ah[mt] = *(const bf16x8*)(a2h + ao);
            Am[mt] = *(const bf16x8*)(a2m + ao);
            Al[mt] = *(const bf16x8*)(a2l + ao);
        }
        #pragma unroll
        for (int nt = 0; nt < 3; ++nt) {
            int bo = brow1[nt] + ka;
            bf16x8 Bh = *(const bf16x8*)(wsp + W1H + bo);
            bf16x8 Bm = *(const bf16x8*)(wsp + W1M + bo);
            bf16x8 Bl = *(const bf16x8*)(wsp + W1L + bo);
            #pragma unroll
            for (int mt = 0; mt < 4; ++mt)
                acc2[mt][nt] = mfma6(Ah[mt], Am[mt], Al[mt], Bh, Bm, Bl, acc2[mt][nt]);
        }
    }
    __syncthreads();   // A2 plane reads done before zs epilogue overwrites region
    #pragma unroll
    for (int mt = 0; mt < 4; ++mt)
        #pragma unroll
        for (int nt = 0; nt < 3; ++nt)
            #pragma unroll
            for (int i = 0; i < 4; ++i) {
                int row = mt * 16 + quad * 4 + i;
                int col = cw + nt * 16 + ln;
                zs[row * ZS_STRIDE + col] = acc2[mt][nt][i];
            }
    __syncthreads();

    // ------- cumprod layer 1
    if (tid < 192) {
        int gi = tid >> 6;
        int r  = tid & 63;
        float* zrow = zs + r * ZS_STRIDE + gi * 64;
        const float* btg = bt1 + gi * 64;
        float p = 1.0f;
        for (int n = 0; n < 64; ++n) {
            p *= fast_cos(zrow[n] + btg[n]);
            zrow[n] = p;
        }
    }
    __syncthreads();

    // ------- gates + two-pass LayerNorm layer 1 -> out0 directly (+ out3/out4)
    {
        int r = tid >> 2;
        int j = tid & 3;
        long tbrow = rowbase + r;
        bool lastt = (tbrow >= LASTROW);
        int bidx = (int)(tbrow - LASTROW);
        const float* zr = zs + r * ZS_STRIDE;
        float h[16];
        float s = 0.f;
        #pragma unroll
        for (int i = 0; i < 16; ++i) {
            int n = j * 16 + i;
            float q1 = zr[n];
            float q2 = zr[64 + n];
            float q3 = zr[128 + n];
            float ig = fast_sigmoid(q1);
            float gg = fast_tanh_pos(fast_sigmoid(q2));
            float og = fast_sigmoid(q3);
            float c  = ig * gg;
            float hv = og * fast_tanh_pos(c);
            h[i] = hv;
            s += hv;
            if (lastt) out4[bidx * 64 + n] = c;
        }
        s += __shfl_xor(s, 1);  s += __shfl_xor(s, 2);
        float mu = s * (1.0f / 64.0f);
        float s2 = 0.f;
        #pragma unroll
        for (int i = 0; i < 16; ++i) {
            float d = h[i] - mu;
            s2 += d * d;
        }
        s2 += __shfl_xor(s2, 1); s2 += __shfl_xor(s2, 2);
        float var = s2 * (1.0f / 64.0f);
        float rs  = rsqrtf(var + 1e-5f);
        float o4[16];
        #pragma unroll
        for (int i = 0; i < 16; ++i)
            o4[i] = (h[i] - mu) * rs * g1[j * 16 + i] + be1[j * 16 + i];
        float* dst = out0 + tbrow * 64 + j * 16;
        #pragma unroll
        for (int i4 = 0; i4 < 4; ++i4)
            *(float4*)(dst + i4 * 4) = *(float4*)(o4 + i4 * 4);
        if (lastt) {
            float* dst3 = out3 + (long)bidx * 64 + j * 16;
            #pragma unroll
            for (int i4 = 0; i4 < 4; ++i4)
                *(float4*)(dst3 + i4 * 4) = *(float4*)(o4 + i4 * 4);
        }
    }
}

extern "C" void kernel_launch(void* const* d_in, const int* in_sizes, int n_in,
                              void* d_out, int out_size, void* d_ws, size_t ws_size,
                              hipStream_t stream) {
    const float* x   = (const float*)d_in[0];
    const float* W0  = (const float*)d_in[1];
    const float* b0  = (const float*)d_in[2];
    const float* th0 = (const float*)d_in[3];
    const float* g0  = (const float*)d_in[4];
    const float* be0 = (const float*)d_in[5];
    const float* W1  = (const float*)d_in[6];
    const float* b1  = (const float*)d_in[7];
    const float* th1 = (const float*)d_in[8];
    const float* g1  = (const float*)d_in[9];
    const float* be1 = (const float*)d_in[10];
    short* wsp = (short*)d_ws;     // needs 663552 B

    presplit_w<<<dim3(432), dim3(256), 0, stream>>>(W0, W1, wsp);
    qlstm_fused<<<dim3(1024), dim3(256), 0, stream>>>(
        x, b0, th0, g0, be0, b1, th1, g1, be1, wsp, (float*)d_out);
}